// Round 4
// baseline (258.444 us; speedup 1.0000x reference)
//
#include <hip/hip_runtime.h>
#include <hip/hip_bf16.h>

typedef __bf16 bf16x8 __attribute__((ext_vector_type(8)));
typedef float f32x4 __attribute__((ext_vector_type(4)));
typedef float f32x8 __attribute__((ext_vector_type(8)));

#define MFMA16(a, b, c) __builtin_amdgcn_mfma_f32_16x16x32_bf16((a), (b), (c), 0, 0, 0)

static __device__ __forceinline__ unsigned short f2b(float f) {
    union { float f; unsigned int u; } v; v.f = f;
    unsigned int r = v.u + 0x7FFFu + ((v.u >> 16) & 1u);  // RNE
    return (unsigned short)(r >> 16);
}

// load 8 fp32, convert to a bf16x8 MFMA fragment
static __device__ __forceinline__ bf16x8 cvt8(const float* p) {
    f32x8 v = *reinterpret_cast<const f32x8*>(p);
    bf16x8 r;
    #pragma unroll
    for (int i = 0; i < 8; ++i) r[i] = (__bf16)v[i];
    return r;
}

// One block = one (b, head, window) task. 256 threads = 4 waves.
// All matmuls C = A * B^T, A (MxK) and B (NxK) row-major. mfma 16x16x32 bf16:
// a/b-frag lane l holds row/col (l&15), k = (l>>4)*8 + i;
// D: col = lane&15, row = (lane>>4)*4 + reg.
__global__ __launch_bounds__(256) void swca_fused(
    const float* __restrict__ qf,
    const float* __restrict__ kf,
    const float* __restrict__ vf,
    const float* __restrict__ Wq,
    const float* __restrict__ Wk,
    const float* __restrict__ Wv,
    const float* __restrict__ Wl,
    const float* __restrict__ pe,
    float* __restrict__ out,
    float* __restrict__ attn,
    int nblk)
{
    __shared__ unsigned short Qs[64][72];  // Q, later O
    __shared__ unsigned short Ks[64][72];  // K
    __shared__ unsigned short Vt[64][72];  // V^T (Vt[e][k])
    __shared__ unsigned short Ps[64][72];  // P (bf16, PV operand)

    // XCD-chunked swizzle: 12 consecutive tasks (heads of one (b,win)) share an XCD L2
    int bid = blockIdx.x;
    const int nper = nblk >> 3;
    int task = (bid & 7) * nper + (bid >> 3);

    const int head = task % 12; task /= 12;
    const int win  = task & 63;
    const int b    = task >> 6;
    const int wy = win >> 3, wx = win & 7;

    const int tid  = threadIdx.x;
    const int wid  = tid >> 6;
    const int lane = tid & 63;
    const int lg   = lane >> 4;   // k-group 0..3
    const int lc   = lane & 15;   // row/col within 16-tile
    const int srow = wid * 16 + lc;  // this lane's A-fragment row

    // shifted-window gather: window row s -> global (y,x) with +4 roll
    const int sy = srow >> 3, sx = srow & 7;
    const int gy = (wy * 8 + sy + 4) & 63;
    const int gx = (wx * 8 + sx + 4) & 63;
    const long rowbase = ((long)b * 4096 + gy * 64 + gx) * 768 + head * 64;

    auto ld8 = [](const unsigned short* p) -> bf16x8 {
        return *reinterpret_cast<const bf16x8*>(p);
    };

    // ---------------- Phase 1: projections ----------------
    bf16x8 qa0 = cvt8(qf + rowbase + lg * 8);
    bf16x8 qa1 = cvt8(qf + rowbase + 32 + lg * 8);
    bf16x8 ka0 = cvt8(kf + rowbase + lg * 8);
    bf16x8 ka1 = cvt8(kf + rowbase + 32 + lg * 8);
    bf16x8 vb0 = cvt8(vf + rowbase + lg * 8);
    bf16x8 vb1 = cvt8(vf + rowbase + 32 + lg * 8);

    // W fragment offset: row (t*16+lc), k (kh*32 + lg*8); rows are 64 elems
    const int wf = lc * 64 + lg * 8;   // + t*1024 + kh*32

    { // Q = qw * Wq^T
        f32x4 acc[4] = {};
        #pragma unroll
        for (int t = 0; t < 4; ++t) {
            acc[t] = MFMA16(qa0, cvt8(Wq + t * 1024 + wf), acc[t]);
            acc[t] = MFMA16(qa1, cvt8(Wq + t * 1024 + 32 + wf), acc[t]);
        }
        #pragma unroll
        for (int t = 0; t < 4; ++t)
            #pragma unroll
            for (int j = 0; j < 4; ++j)
                Qs[wid * 16 + lg * 4 + j][t * 16 + lc] = f2b(acc[t][j]);
    }
    { // K = kw * Wk^T
        f32x4 acc[4] = {};
        #pragma unroll
        for (int t = 0; t < 4; ++t) {
            acc[t] = MFMA16(ka0, cvt8(Wk + t * 1024 + wf), acc[t]);
            acc[t] = MFMA16(ka1, cvt8(Wk + t * 1024 + 32 + wf), acc[t]);
        }
        #pragma unroll
        for (int t = 0; t < 4; ++t)
            #pragma unroll
            for (int j = 0; j < 4; ++j)
                Ks[wid * 16 + lg * 4 + j][t * 16 + lc] = f2b(acc[t][j]);
    }
    { // V^T = Wv * vw^T
        f32x4 acc[4] = {};
        #pragma unroll
        for (int t = 0; t < 4; ++t) {
            acc[t] = MFMA16(cvt8(Wv + t * 1024 + wf), vb0, acc[t]);
            acc[t] = MFMA16(cvt8(Wv + t * 1024 + 32 + wf), vb1, acc[t]);
        }
        #pragma unroll
        for (int t = 0; t < 4; ++t)
            #pragma unroll
            for (int j = 0; j < 4; ++j)
                Vt[t * 16 + lg * 4 + j][wid * 16 + lc] = f2b(acc[t][j]);
    }
    __syncthreads();

    // ---------------- Phase 2: S = QK^T/8 + bias + mask, softmax ----------------
    f32x4 accS[4] = {};
    {
        bf16x8 a0 = ld8(&Qs[srow][lg * 8]);
        bf16x8 a1 = ld8(&Qs[srow][32 + lg * 8]);
        #pragma unroll
        for (int t = 0; t < 4; ++t) {
            accS[t] = MFMA16(a0, ld8(&Ks[t * 16 + lc][lg * 8]), accS[t]);
            accS[t] = MFMA16(a1, ld8(&Ks[t * 16 + lc][32 + lg * 8]), accS[t]);
        }
    }
    const int r0 = wid * 16 + lg * 4;
    {
        float sv[4][4];
        #pragma unroll
        for (int t = 0; t < 4; ++t) {
            const int c = t * 16 + lc, ky = c >> 3, kx = c & 7;
            #pragma unroll
            for (int j = 0; j < 4; ++j) {
                const int r = r0 + j, qy = r >> 3, qx = r & 7;
                const float biasv = pe[(ky - qy + 7) * 15 + (kx - qx + 7)];
                const bool msk = ((wy == 7) && (((qy ^ ky) & 4) != 0)) ||
                                 ((wx == 7) && (((qx ^ kx) & 4) != 0));
                sv[t][j] = msk ? -__builtin_inff() : accS[t][j] * 0.125f + biasv;
            }
        }
        float pv[4][4];
        #pragma unroll
        for (int j = 0; j < 4; ++j) {
            float mx = fmaxf(fmaxf(sv[0][j], sv[1][j]), fmaxf(sv[2][j], sv[3][j]));
            mx = fmaxf(mx, __shfl_xor(mx, 1));
            mx = fmaxf(mx, __shfl_xor(mx, 2));
            mx = fmaxf(mx, __shfl_xor(mx, 4));
            mx = fmaxf(mx, __shfl_xor(mx, 8));   // row lives in one 16-lane group
            const float e0 = __expf(sv[0][j] - mx);
            const float e1 = __expf(sv[1][j] - mx);
            const float e2 = __expf(sv[2][j] - mx);
            const float e3 = __expf(sv[3][j] - mx);
            float sm = (e0 + e1) + (e2 + e3);
            sm += __shfl_xor(sm, 1);
            sm += __shfl_xor(sm, 2);
            sm += __shfl_xor(sm, 4);
            sm += __shfl_xor(sm, 8);
            const float inv = 1.0f / sm;
            pv[0][j] = e0 * inv; pv[1][j] = e1 * inv;
            pv[2][j] = e2 * inv; pv[3][j] = e3 * inv;
        }
        // attn out (fp32, direct): 16 lanes cover 64B contiguous per (t,j)
        const long abase0 = ((((long)b * 12 + head) * 64 + win) * 64 + r0) * 64;
        #pragma unroll
        for (int j = 0; j < 4; ++j)
            #pragma unroll
            for (int t = 0; t < 4; ++t)
                attn[abase0 + (long)j * 64 + t * 16 + lc] = pv[t][j];
        // P (bf16) for the PV matmul
        #pragma unroll
        for (int t = 0; t < 4; ++t)
            #pragma unroll
            for (int j = 0; j < 4; ++j)
                Ps[r0 + j][t * 16 + lc] = f2b(pv[t][j]);
    }
    __syncthreads();

    // ---------------- Phase 3: O = P * V ----------------
    {
        bf16x8 a0 = ld8(&Ps[srow][lg * 8]);
        bf16x8 a1 = ld8(&Ps[srow][32 + lg * 8]);
        f32x4 acc[4] = {};
        #pragma unroll
        for (int t = 0; t < 4; ++t) {
            acc[t] = MFMA16(a0, ld8(&Vt[t * 16 + lc][lg * 8]), acc[t]);
            acc[t] = MFMA16(a1, ld8(&Vt[t * 16 + lc][32 + lg * 8]), acc[t]);
        }
        #pragma unroll
        for (int t = 0; t < 4; ++t)   // O overwrites Qs (dead after phase 2)
            #pragma unroll
            for (int j = 0; j < 4; ++j)
                Qs[wid * 16 + lg * 4 + j][t * 16 + lc] = f2b(acc[t][j]);
    }
    __syncthreads();

    // ---------------- Phase 4: F = O * Wlin^T, direct fp32 scatter ----------------
    {
        bf16x8 a0 = ld8(&Qs[srow][lg * 8]);
        bf16x8 a1 = ld8(&Qs[srow][32 + lg * 8]);
        f32x4 acc[4] = {};
        #pragma unroll
        for (int t = 0; t < 4; ++t) {
            acc[t] = MFMA16(a0, cvt8(Wl + t * 1024 + wf), acc[t]);
            acc[t] = MFMA16(a1, cvt8(Wl + t * 1024 + 32 + wf), acc[t]);
        }
        // lane holds F rows r0..r0+3, col e = t*16+lc; scatter with +4 roll
        #pragma unroll
        for (int j = 0; j < 4; ++j) {
            const int r = r0 + j, ry = r >> 3, rx = r & 7;
            const int oy = (wy * 8 + ry + 4) & 63;
            const int ox = (wx * 8 + rx + 4) & 63;
            const long obase = ((long)b * 4096 + oy * 64 + ox) * 768 + head * 64;
            #pragma unroll
            for (int t = 0; t < 4; ++t)
                out[obase + t * 16 + lc] = acc[t][j];
        }
    }
}

extern "C" void kernel_launch(void* const* d_in, const int* in_sizes, int n_in,
                              void* d_out, int out_size, void* d_ws, size_t ws_size,
                              hipStream_t stream) {
    const float* qf = (const float*)d_in[0];
    const float* kf = (const float*)d_in[1];
    const float* vf = (const float*)d_in[2];
    const float* Wq = (const float*)d_in[3];
    const float* Wk = (const float*)d_in[4];
    const float* Wv = (const float*)d_in[5];
    const float* Wl = (const float*)d_in[6];
    const float* pe = (const float*)d_in[7];

    const int B = in_sizes[0] / (4096 * 768);   // 8
    float* outp = (float*)d_out;
    float* attnp = outp + (size_t)B * 4096 * 768;

    const int nblk = B * 768;   // (b, win, head) tasks, head fastest
    swca_fused<<<nblk, 256, 0, stream>>>(qf, kf, vf, Wq, Wk, Wv, Wl, pe,
                                         outp, attnp, nblk);
}

// Round 5
// 230.796 us; speedup vs baseline: 1.1198x; 1.1198x over previous
//
#include <hip/hip_runtime.h>
#include <hip/hip_bf16.h>

typedef __bf16 bf16x8 __attribute__((ext_vector_type(8)));
typedef float f32x4 __attribute__((ext_vector_type(4)));
typedef float f32x8 __attribute__((ext_vector_type(8)));

#define MFMA16(a, b, c) __builtin_amdgcn_mfma_f32_16x16x32_bf16((a), (b), (c), 0, 0, 0)

static __device__ __forceinline__ unsigned short f2b(float f) {
    union { float f; unsigned int u; } v; v.f = f;
    unsigned int r = v.u + 0x7FFFu + ((v.u >> 16) & 1u);  // RNE
    return (unsigned short)(r >> 16);
}

// load 8 fp32, convert to a bf16x8 MFMA fragment
static __device__ __forceinline__ bf16x8 cvt8(const float* p) {
    f32x8 v = *reinterpret_cast<const f32x8*>(p);
    bf16x8 r;
    #pragma unroll
    for (int i = 0; i < 8; ++i) r[i] = (__bf16)v[i];
    return r;
}

#define PITCH 68

// One block = one (b, head, window) task. 256 threads = 4 waves.
// ONE barrier total: only K and V^T cross waves. Q/P/O live in a single
// wave-private LDS buffer (As) — same-wave LDS ops are in-order, no sync
// needed. mfma 16x16x32 bf16 layout: a/b-frag lane l holds row/col (l&15),
// k = (l>>4)*8 + i; D: col = lane&15, row = (lane>>4)*4 + reg.
__global__ __launch_bounds__(256) void swca_fused(
    const float* __restrict__ qf,
    const float* __restrict__ kf,
    const float* __restrict__ vf,
    const float* __restrict__ Wq,
    const float* __restrict__ Wk,
    const float* __restrict__ Wv,
    const float* __restrict__ Wl,
    const float* __restrict__ pe,
    float* __restrict__ out,
    float* __restrict__ attn,
    int nblk)
{
    __shared__ unsigned short As[64][PITCH];  // Q -> P -> O (wave-private bands)
    __shared__ unsigned short Ks[64][PITCH];  // K   (cross-wave, persistent)
    __shared__ unsigned short Vt[64][PITCH];  // V^T (cross-wave, persistent)

    // XCD-chunked swizzle: 12 consecutive tasks (heads of one (b,win)) share an XCD L2
    int bid = blockIdx.x;
    const int nper = nblk >> 3;
    int task = (bid & 7) * nper + (bid >> 3);

    const int head = task % 12; task /= 12;
    const int win  = task & 63;
    const int b    = task >> 6;
    const int wy = win >> 3, wx = win & 7;

    const int tid  = threadIdx.x;
    const int wid  = tid >> 6;
    const int lane = tid & 63;
    const int lg   = lane >> 4;   // k-group 0..3
    const int lc   = lane & 15;   // row/col within 16-tile
    const int srow = wid * 16 + lc;  // this lane's A-fragment row

    // shifted-window gather: window row s -> global (y,x) with +4 roll
    const int sy = srow >> 3, sx = srow & 7;
    const int gy = (wy * 8 + sy + 4) & 63;
    const int gx = (wx * 8 + sx + 4) & 63;
    const long rowbase = ((long)b * 4096 + gy * 64 + gx) * 768 + head * 64;

    auto ld8 = [](const unsigned short* p) -> bf16x8 {
        return *reinterpret_cast<const bf16x8*>(p);
    };

    // issue all feature loads up front (hide HBM latency)
    bf16x8 ka0 = cvt8(kf + rowbase + lg * 8);
    bf16x8 ka1 = cvt8(kf + rowbase + 32 + lg * 8);
    bf16x8 vb0 = cvt8(vf + rowbase + lg * 8);
    bf16x8 vb1 = cvt8(vf + rowbase + 32 + lg * 8);
    bf16x8 qa0 = cvt8(qf + rowbase + lg * 8);
    bf16x8 qa1 = cvt8(qf + rowbase + 32 + lg * 8);

    // W fragment offset: row (t*16+lc), k (kh*32 + lg*8); rows are 64 elems
    const int wf = lc * 64 + lg * 8;   // + t*1024 + kh*32

    // ---------------- pre-barrier: K and V^T (cross-wave) ----------------
    { // K = kw * Wk^T
        f32x4 acc[4] = {};
        #pragma unroll
        for (int t = 0; t < 4; ++t) {
            acc[t] = MFMA16(ka0, cvt8(Wk + t * 1024 + wf), acc[t]);
            acc[t] = MFMA16(ka1, cvt8(Wk + t * 1024 + 32 + wf), acc[t]);
        }
        #pragma unroll
        for (int t = 0; t < 4; ++t)
            #pragma unroll
            for (int j = 0; j < 4; ++j)
                Ks[wid * 16 + lg * 4 + j][t * 16 + lc] = f2b(acc[t][j]);
    }
    { // V^T = Wv * vw^T
        f32x4 acc[4] = {};
        #pragma unroll
        for (int t = 0; t < 4; ++t) {
            acc[t] = MFMA16(cvt8(Wv + t * 1024 + wf), vb0, acc[t]);
            acc[t] = MFMA16(cvt8(Wv + t * 1024 + 32 + wf), vb1, acc[t]);
        }
        #pragma unroll
        for (int t = 0; t < 4; ++t)
            #pragma unroll
            for (int j = 0; j < 4; ++j)
                Vt[t * 16 + lg * 4 + j][wid * 16 + lc] = f2b(acc[t][j]);
    }
    __syncthreads();   // the ONLY barrier

    // ---------------- post-barrier: everything wave-local ----------------
    { // Q = qw * Wq^T  (wave-private band of As)
        f32x4 acc[4] = {};
        #pragma unroll
        for (int t = 0; t < 4; ++t) {
            acc[t] = MFMA16(qa0, cvt8(Wq + t * 1024 + wf), acc[t]);
            acc[t] = MFMA16(qa1, cvt8(Wq + t * 1024 + 32 + wf), acc[t]);
        }
        #pragma unroll
        for (int t = 0; t < 4; ++t)
            #pragma unroll
            for (int j = 0; j < 4; ++j)
                As[wid * 16 + lg * 4 + j][t * 16 + lc] = f2b(acc[t][j]);
    }

    // S = QK^T/8 + bias + mask, softmax
    f32x4 accS[4] = {};
    {
        bf16x8 a0 = ld8(&As[srow][lg * 8]);
        bf16x8 a1 = ld8(&As[srow][32 + lg * 8]);
        #pragma unroll
        for (int t = 0; t < 4; ++t) {
            accS[t] = MFMA16(a0, ld8(&Ks[t * 16 + lc][lg * 8]), accS[t]);
            accS[t] = MFMA16(a1, ld8(&Ks[t * 16 + lc][32 + lg * 8]), accS[t]);
        }
    }
    const int r0 = wid * 16 + lg * 4;
    {
        float sv[4][4];
        #pragma unroll
        for (int t = 0; t < 4; ++t) {
            const int c = t * 16 + lc, ky = c >> 3, kx = c & 7;
            #pragma unroll
            for (int j = 0; j < 4; ++j) {
                const int r = r0 + j, qy = r >> 3, qx = r & 7;
                const float biasv = pe[(ky - qy + 7) * 15 + (kx - qx + 7)];
                const bool msk = ((wy == 7) && (((qy ^ ky) & 4) != 0)) ||
                                 ((wx == 7) && (((qx ^ kx) & 4) != 0));
                sv[t][j] = msk ? -__builtin_inff() : accS[t][j] * 0.125f + biasv;
            }
        }
        float pv[4][4];
        #pragma unroll
        for (int j = 0; j < 4; ++j) {
            float mx = fmaxf(fmaxf(sv[0][j], sv[1][j]), fmaxf(sv[2][j], sv[3][j]));
            mx = fmaxf(mx, __shfl_xor(mx, 1));
            mx = fmaxf(mx, __shfl_xor(mx, 2));
            mx = fmaxf(mx, __shfl_xor(mx, 4));
            mx = fmaxf(mx, __shfl_xor(mx, 8));   // row lives in one 16-lane group
            const float e0 = __expf(sv[0][j] - mx);
            const float e1 = __expf(sv[1][j] - mx);
            const float e2 = __expf(sv[2][j] - mx);
            const float e3 = __expf(sv[3][j] - mx);
            float sm = (e0 + e1) + (e2 + e3);
            sm += __shfl_xor(sm, 1);
            sm += __shfl_xor(sm, 2);
            sm += __shfl_xor(sm, 4);
            sm += __shfl_xor(sm, 8);
            const float inv = 1.0f / sm;
            pv[0][j] = e0 * inv; pv[1][j] = e1 * inv;
            pv[2][j] = e2 * inv; pv[3][j] = e3 * inv;
        }
        // attn out (fp32, direct from regs)
        const long abase0 = ((((long)b * 12 + head) * 64 + win) * 64 + r0) * 64;
        #pragma unroll
        for (int j = 0; j < 4; ++j)
            #pragma unroll
            for (int t = 0; t < 4; ++t)
                attn[abase0 + (long)j * 64 + t * 16 + lc] = pv[t][j];
        // P (bf16) overwrites Q in the wave-private band (in-order LDS: safe)
        #pragma unroll
        for (int t = 0; t < 4; ++t)
            #pragma unroll
            for (int j = 0; j < 4; ++j)
                As[r0 + j][t * 16 + lc] = f2b(pv[t][j]);
    }

    // O = P * V   (P read then O written into the same band: in-order, safe)
    {
        bf16x8 a0 = ld8(&As[srow][lg * 8]);
        bf16x8 a1 = ld8(&As[srow][32 + lg * 8]);
        f32x4 acc[4] = {};
        #pragma unroll
        for (int t = 0; t < 4; ++t) {
            acc[t] = MFMA16(a0, ld8(&Vt[t * 16 + lc][lg * 8]), acc[t]);
            acc[t] = MFMA16(a1, ld8(&Vt[t * 16 + lc][32 + lg * 8]), acc[t]);
        }
        #pragma unroll
        for (int t = 0; t < 4; ++t)
            #pragma unroll
            for (int j = 0; j < 4; ++j)
                As[wid * 16 + lg * 4 + j][t * 16 + lc] = f2b(acc[t][j]);
    }

    // F = O * Wlin^T, direct fp32 scatter
    {
        bf16x8 a0 = ld8(&As[srow][lg * 8]);
        bf16x8 a1 = ld8(&As[srow][32 + lg * 8]);
        f32x4 acc[4] = {};
        #pragma unroll
        for (int t = 0; t < 4; ++t) {
            acc[t] = MFMA16(a0, cvt8(Wl + t * 1024 + wf), acc[t]);
            acc[t] = MFMA16(a1, cvt8(Wl + t * 1024 + 32 + wf), acc[t]);
        }
        // lane holds F rows r0..r0+3, col e = t*16+lc; scatter with +4 roll
        #pragma unroll
        for (int j = 0; j < 4; ++j) {
            const int r = r0 + j, ry = r >> 3, rx = r & 7;
            const int oy = (wy * 8 + ry + 4) & 63;
            const int ox = (wx * 8 + rx + 4) & 63;
            const long obase = ((long)b * 4096 + oy * 64 + ox) * 768 + head * 64;
            #pragma unroll
            for (int t = 0; t < 4; ++t)
                out[obase + t * 16 + lc] = acc[t][j];
        }
    }
}

extern "C" void kernel_launch(void* const* d_in, const int* in_sizes, int n_in,
                              void* d_out, int out_size, void* d_ws, size_t ws_size,
                              hipStream_t stream) {
    const float* qf = (const float*)d_in[0];
    const float* kf = (const float*)d_in[1];
    const float* vf = (const float*)d_in[2];
    const float* Wq = (const float*)d_in[3];
    const float* Wk = (const float*)d_in[4];
    const float* Wv = (const float*)d_in[5];
    const float* Wl = (const float*)d_in[6];
    const float* pe = (const float*)d_in[7];

    const int B = in_sizes[0] / (4096 * 768);   // 8
    float* outp = (float*)d_out;
    float* attnp = outp + (size_t)B * 4096 * 768;

    const int nblk = B * 768;   // (b, win, head) tasks, head fastest
    swca_fused<<<nblk, 256, 0, stream>>>(qf, kf, vf, Wq, Wk, Wv, Wl, pe,
                                         outp, attnp, nblk);
}

// Round 6
// 139.064 us; speedup vs baseline: 1.8585x; 1.6596x over previous
//
#include <hip/hip_runtime.h>
#include <hip/hip_bf16.h>

typedef __bf16 bf16x8 __attribute__((ext_vector_type(8)));
typedef float f32x4 __attribute__((ext_vector_type(4)));
typedef float f32x8 __attribute__((ext_vector_type(8)));

#define MFMA16(a, b, c) __builtin_amdgcn_mfma_f32_16x16x32_bf16((a), (b), (c), 0, 0, 0)

static __device__ __forceinline__ unsigned short f2b(float f) {
    union { float f; unsigned int u; } v; v.f = f;
    unsigned int r = v.u + 0x7FFFu + ((v.u >> 16) & 1u);  // RNE
    return (unsigned short)(r >> 16);
}

// load 8 fp32, convert to a bf16x8 MFMA fragment
static __device__ __forceinline__ bf16x8 cvt8(const float* p) {
    f32x8 v = *reinterpret_cast<const f32x8*>(p);
    bf16x8 r;
    #pragma unroll
    for (int i = 0; i < 8; ++i) r[i] = (__bf16)v[i];
    return r;
}

// ---------------- precompute: Mt = (Wq^T Wk)^T, N = Wl*Wv  (bf16, in d_ws) ----
// Mt[dp][d] = sum_e Wq[e][d] * Wk[e][dp]      (B-operand for T = qw * Mt^T)
// N [e][d]  = sum_c Wl[e][c] * Wv[c][d]       (B-operand for F = U * N^T)
__global__ __launch_bounds__(256) void precompute_mn(
    const float* __restrict__ Wq, const float* __restrict__ Wk,
    const float* __restrict__ Wv, const float* __restrict__ Wl,
    unsigned short* __restrict__ ws)
{
    __shared__ float A[4096], B[4096];
    const int bid = blockIdx.x;          // 8 blocks
    const int which = bid >> 2;          // 0 = Mt, 1 = N
    const int rq = bid & 3;              // row quad
    const int tid = threadIdx.x;
    for (int i = tid; i < 4096; i += 256) {
        A[i] = which ? Wl[i] : Wq[i];
        B[i] = which ? Wv[i] : Wk[i];
    }
    __syncthreads();
    const int row = rq * 16 + (tid >> 4);
    const int c0  = tid & 15;
    float acc[4] = {0, 0, 0, 0};
    if (which == 0) {        // Mt[row][col] = sum_e Wq[e][col] * Wk[e][row]
        for (int e = 0; e < 64; ++e) {
            const float s = B[e * 64 + row];
            #pragma unroll
            for (int i = 0; i < 4; ++i) acc[i] += A[e * 64 + c0 + 16 * i] * s;
        }
    } else {                 // N[row][col] = sum_c Wl[row][c] * Wv[c][col]
        for (int c = 0; c < 64; ++c) {
            const float s = A[row * 64 + c];
            #pragma unroll
            for (int i = 0; i < 4; ++i) acc[i] += s * B[c * 64 + c0 + 16 * i];
        }
    }
    #pragma unroll
    for (int i = 0; i < 4; ++i)
        ws[which * 4096 + row * 64 + c0 + 16 * i] = f2b(acc[i]);
}

#define PITCH 68

// One block = TWO (b, head, window) tasks (paired heads of the same window),
// 512 threads = 8 waves, 4 per task. Chain per task (post-barrier, all
// wave-local): T = qw*Mt^T -> S = T*kw^T (/8 + bias + mask, softmax) ->
// U = P*vw -> F = U*N^T. kw/vw are staged RAW (no projection matmuls).
// mfma 16x16x32 bf16: a/b-frag lane l holds row/col (l&15), k=(l>>4)*8+i;
// D: col = lane&15, row = (lane>>4)*4 + reg.
__global__ __launch_bounds__(512) void swca_fused(
    const float* __restrict__ qf,
    const float* __restrict__ kf,
    const float* __restrict__ vf,
    const unsigned short* __restrict__ Mt,   // ws
    const unsigned short* __restrict__ Nw,   // ws + 4096
    const float* __restrict__ pe,
    float* __restrict__ out,
    float* __restrict__ attn,
    int nblk2)
{
    __shared__ unsigned short kwS[2][64][PITCH];  // raw K features (bf16)
    __shared__ unsigned short vwT[2][64][PITCH];  // raw V features, transposed
    __shared__ unsigned short As[2][64][PITCH];   // T -> P -> U (wave-private bands)

    int bid = blockIdx.x;
    const int nper = nblk2 >> 3;                 // XCD-chunked swizzle
    const int task2 = (bid & 7) * nper + (bid >> 3);

    const int tid = threadIdx.x;
    const int h2  = tid >> 8;                    // which task half
    int task = task2 * 2 + h2;

    const int head = task % 12; task /= 12;
    const int win  = task & 63;
    const int b    = task >> 6;
    const int wy = win >> 3, wx = win & 7;

    const int tt   = tid & 255;
    const int wid  = tt >> 6;
    const int lane = tt & 63;
    const int lg   = lane >> 4;   // k-group 0..3
    const int lc   = lane & 15;   // row/col within 16-tile
    const int srow = wid * 16 + lc;

    // shifted-window gather: window row s -> global (y,x) with +4 roll
    const int sy = srow >> 3, sx = srow & 7;
    const int gy = (wy * 8 + sy + 4) & 63;
    const int gx = (wx * 8 + sx + 4) & 63;
    const long rowbase = ((long)b * 4096 + gy * 64 + gx) * 768 + head * 64;

    auto ld8 = [](const unsigned short* p) -> bf16x8 {
        return *reinterpret_cast<const bf16x8*>(p);
    };

    // ---------------- staging (no MFMA before the barrier) ----------------
    bf16x8 qa0 = cvt8(qf + rowbase + lg * 8);
    bf16x8 qa1 = cvt8(qf + rowbase + 32 + lg * 8);
    bf16x8 kb0 = cvt8(kf + rowbase + lg * 8);
    bf16x8 kb1 = cvt8(kf + rowbase + 32 + lg * 8);
    f32x8 vb0 = *reinterpret_cast<const f32x8*>(vf + rowbase + lg * 8);
    f32x8 vb1 = *reinterpret_cast<const f32x8*>(vf + rowbase + 32 + lg * 8);

    *reinterpret_cast<bf16x8*>(&kwS[h2][srow][lg * 8]) = kb0;       // b128 writes
    *reinterpret_cast<bf16x8*>(&kwS[h2][srow][32 + lg * 8]) = kb1;
    #pragma unroll
    for (int i = 0; i < 8; ++i) {                                    // transpose scatter
        vwT[h2][lg * 8 + i][srow] = f2b(vb0[i]);
        vwT[h2][32 + lg * 8 + i][srow] = f2b(vb1[i]);
    }
    __syncthreads();   // the ONLY barrier

    // ---------------- T = qw * Mt^T  (wave-private band) ----------------
    {
        f32x4 acc[4] = {};
        #pragma unroll
        for (int t = 0; t < 4; ++t) {
            acc[t] = MFMA16(qa0, ld8(Mt + (t * 16 + lc) * 64 + lg * 8), acc[t]);
            acc[t] = MFMA16(qa1, ld8(Mt + (t * 16 + lc) * 64 + 32 + lg * 8), acc[t]);
        }
        #pragma unroll
        for (int t = 0; t < 4; ++t)
            #pragma unroll
            for (int j = 0; j < 4; ++j)
                As[h2][wid * 16 + lg * 4 + j][t * 16 + lc] = f2b(acc[t][j]);
    }

    // ---------------- S = T * kw^T (/8 + bias + mask), softmax ----------------
    f32x4 accS[4] = {};
    {
        bf16x8 a0 = ld8(&As[h2][srow][lg * 8]);
        bf16x8 a1 = ld8(&As[h2][srow][32 + lg * 8]);
        #pragma unroll
        for (int t = 0; t < 4; ++t) {
            accS[t] = MFMA16(a0, ld8(&kwS[h2][t * 16 + lc][lg * 8]), accS[t]);
            accS[t] = MFMA16(a1, ld8(&kwS[h2][t * 16 + lc][32 + lg * 8]), accS[t]);
        }
    }
    const int r0 = wid * 16 + lg * 4;
    {
        float sv[4][4];
        #pragma unroll
        for (int t = 0; t < 4; ++t) {
            const int c = t * 16 + lc, ky = c >> 3, kx = c & 7;
            #pragma unroll
            for (int j = 0; j < 4; ++j) {
                const int r = r0 + j, qy = r >> 3, qx = r & 7;
                const float biasv = pe[(ky - qy + 7) * 15 + (kx - qx + 7)];
                const bool msk = ((wy == 7) && (((qy ^ ky) & 4) != 0)) ||
                                 ((wx == 7) && (((qx ^ kx) & 4) != 0));
                sv[t][j] = msk ? -__builtin_inff() : accS[t][j] * 0.125f + biasv;
            }
        }
        float pv[4][4];
        #pragma unroll
        for (int j = 0; j < 4; ++j) {
            float mx = fmaxf(fmaxf(sv[0][j], sv[1][j]), fmaxf(sv[2][j], sv[3][j]));
            mx = fmaxf(mx, __shfl_xor(mx, 1));
            mx = fmaxf(mx, __shfl_xor(mx, 2));
            mx = fmaxf(mx, __shfl_xor(mx, 4));
            mx = fmaxf(mx, __shfl_xor(mx, 8));   // row lives in one 16-lane group
            const float e0 = __expf(sv[0][j] - mx);
            const float e1 = __expf(sv[1][j] - mx);
            const float e2 = __expf(sv[2][j] - mx);
            const float e3 = __expf(sv[3][j] - mx);
            float sm = (e0 + e1) + (e2 + e3);
            sm += __shfl_xor(sm, 1);
            sm += __shfl_xor(sm, 2);
            sm += __shfl_xor(sm, 4);
            sm += __shfl_xor(sm, 8);
            const float inv = 1.0f / sm;
            pv[0][j] = e0 * inv; pv[1][j] = e1 * inv;
            pv[2][j] = e2 * inv; pv[3][j] = e3 * inv;
        }
        // attn out (fp32, direct from regs)
        const long abase0 = ((((long)b * 12 + head) * 64 + win) * 64 + r0) * 64;
        #pragma unroll
        for (int j = 0; j < 4; ++j)
            #pragma unroll
            for (int t = 0; t < 4; ++t)
                attn[abase0 + (long)j * 64 + t * 16 + lc] = pv[t][j];
        // P (bf16) overwrites T in the wave-private band (in-order LDS: safe)
        #pragma unroll
        for (int t = 0; t < 4; ++t)
            #pragma unroll
            for (int j = 0; j < 4; ++j)
                As[h2][r0 + j][t * 16 + lc] = f2b(pv[t][j]);
    }

    // ---------------- U = P * vw ----------------
    {
        bf16x8 a0 = ld8(&As[h2][srow][lg * 8]);
        bf16x8 a1 = ld8(&As[h2][srow][32 + lg * 8]);
        f32x4 acc[4] = {};
        #pragma unroll
        for (int t = 0; t < 4; ++t) {
            acc[t] = MFMA16(a0, ld8(&vwT[h2][t * 16 + lc][lg * 8]), acc[t]);
            acc[t] = MFMA16(a1, ld8(&vwT[h2][t * 16 + lc][32 + lg * 8]), acc[t]);
        }
        #pragma unroll
        for (int t = 0; t < 4; ++t)
            #pragma unroll
            for (int j = 0; j < 4; ++j)
                As[h2][wid * 16 + lg * 4 + j][t * 16 + lc] = f2b(acc[t][j]);
    }

    // ---------------- F = U * N^T, direct fp32 scatter ----------------
    {
        bf16x8 a0 = ld8(&As[h2][srow][lg * 8]);
        bf16x8 a1 = ld8(&As[h2][srow][32 + lg * 8]);
        f32x4 acc[4] = {};
        #pragma unroll
        for (int t = 0; t < 4; ++t) {
            acc[t] = MFMA16(a0, ld8(Nw + (t * 16 + lc) * 64 + lg * 8), acc[t]);
            acc[t] = MFMA16(a1, ld8(Nw + (t * 16 + lc) * 64 + 32 + lg * 8), acc[t]);
        }
        #pragma unroll
        for (int j = 0; j < 4; ++j) {
            const int r = r0 + j, ry = r >> 3, rx = r & 7;
            const int oy = (wy * 8 + ry + 4) & 63;
            const int ox = (wx * 8 + rx + 4) & 63;
            const long obase = ((long)b * 4096 + oy * 64 + ox) * 768 + head * 64;
            #pragma unroll
            for (int t = 0; t < 4; ++t)
                out[obase + t * 16 + lc] = acc[t][j];
        }
    }
}

extern "C" void kernel_launch(void* const* d_in, const int* in_sizes, int n_in,
                              void* d_out, int out_size, void* d_ws, size_t ws_size,
                              hipStream_t stream) {
    const float* qf = (const float*)d_in[0];
    const float* kf = (const float*)d_in[1];
    const float* vf = (const float*)d_in[2];
    const float* Wq = (const float*)d_in[3];
    const float* Wk = (const float*)d_in[4];
    const float* Wv = (const float*)d_in[5];
    const float* Wl = (const float*)d_in[6];
    const float* pe = (const float*)d_in[7];

    const int B = in_sizes[0] / (4096 * 768);   // 8
    float* outp = (float*)d_out;
    float* attnp = outp + (size_t)B * 4096 * 768;
    unsigned short* ws = (unsigned short*)d_ws;

    precompute_mn<<<8, 256, 0, stream>>>(Wq, Wk, Wv, Wl, ws);

    const int nblk2 = B * 768 / 2;   // 2 tasks per block
    swca_fused<<<nblk2, 512, 0, stream>>>(qf, kf, vf, ws, ws + 4096, pe,
                                          outp, attnp, nblk2);
}